// Round 1
// baseline (241.246 us; speedup 1.0000x reference)
//
#include <hip/hip_runtime.h>

#define LN 512        // MAX_IN_LENGTH (fixed by the reference)
#define THREADS 256

// ---------------------------------------------------------------------------
// Pre-pass: recover (dilation, tap-sign mask) per output channel from the
// sparse dense weight W[o, 0, 0:K].  Tap layout: first tap at
// p0 = max_pad - 4*d (always a multiple of 4), taps at p0 + j*d, j=0..8,
// values in {-1, 2} (never 0).  mask bit j set <=> tap j == 2.
// ---------------------------------------------------------------------------
__global__ void parse_w_kernel(const float* __restrict__ W, int O, int K,
                               int max_pad, int2* __restrict__ params) {
    int o = blockIdx.x * blockDim.x + threadIdx.x;
    if (o >= O) return;
    const float* row = W + (size_t)o * K;
    int p0 = 0;
    for (int q = 0; q <= max_pad; q += 4) {   // first nonzero is at a multiple of 4
        if (row[q] != 0.0f) { p0 = q; break; }
    }
    int d = (max_pad - p0) >> 2;
    if (d < 1) d = 1;                          // defensive; never hit by construction
    int mask = 0;
#pragma unroll
    for (int j = 0; j < 9; ++j) {
        if (row[p0 + j * d] > 0.5f) mask |= (1 << j);
    }
    params[o] = make_int2(d, mask);
}

// ---------------------------------------------------------------------------
// Main kernel: one block per output row (bc, o).  X row staged in LDS with
// max_pad zeros on each side so the 9-tap gather needs no bounds checks.
// Each lane computes 2 adjacent t's and stores one float2 (rows are 8B-aligned:
// T*4 = 1800 bytes).
// ---------------------------------------------------------------------------
__global__ __launch_bounds__(THREADS) void rocket_kernel(
    const float* __restrict__ X, const float* __restrict__ bias,
    const int2* __restrict__ params, float* __restrict__ out,
    int O, int T, int max_pad) {
    extern __shared__ float xs[];   // LN + 2*max_pad floats, zero-padded edges

    const int row = blockIdx.x;
    const int o   = row % O;
    const int bc  = row / O;

    // stage: zero pads [0, max_pad) and [max_pad+LN, max_pad+LN+max_pad),
    // fill center [max_pad, max_pad+LN) — disjoint regions, single barrier.
    for (int i = threadIdx.x; i < max_pad; i += THREADS) {
        xs[i] = 0.0f;
        xs[max_pad + LN + i] = 0.0f;
    }
    const float* xrow = X + (size_t)bc * LN;
    for (int i = threadIdx.x; i < LN; i += THREADS) {
        xs[max_pad + i] = xrow[i];
    }
    __syncthreads();

    const int2 p    = params[o];
    const int  d    = p.x;
    const int  mask = p.y;
    const float bv  = bias[o];

    const int T2 = T >> 1;
    for (int t2 = threadIdx.x; t2 < T2; t2 += THREADS) {
        const int t    = t2 * 2;
        const int base = max_pad + t - 4 * d;
        float a0 = bv, a1 = bv;
#pragma unroll
        for (int j = 0; j < 9; ++j) {
            const float w  = ((mask >> j) & 1) ? 2.0f : -1.0f;
            const float x0 = xs[base + j * d];
            const float x1 = xs[base + j * d + 1];
            a0 = fmaf(w, x0, a0);
            a1 = fmaf(w, x1, a1);
        }
        float2* orow = (float2*)(out + (size_t)row * T);
        orow[t2] = make_float2(a0, a1);
    }
    // odd-T tail (dead for T=450, kept for safety)
    if ((T & 1) && threadIdx.x == 0) {
        const int t    = T - 1;
        const int base = max_pad + t - 4 * d;
        float a0 = bv;
#pragma unroll
        for (int j = 0; j < 9; ++j) {
            const float w = ((mask >> j) & 1) ? 2.0f : -1.0f;
            a0 = fmaf(w, xs[base + j * d], a0);
        }
        out[(size_t)row * T + t] = a0;
    }
}

extern "C" void kernel_launch(void* const* d_in, const int* in_sizes, int n_in,
                              void* d_out, int out_size, void* d_ws, size_t ws_size,
                              hipStream_t stream) {
    const float* X = (const float*)d_in[0];
    const float* W = (const float*)d_in[1];
    const float* b = (const float*)d_in[2];
    float* out = (float*)d_out;

    const int O       = in_sizes[2];           // 3276
    const int K       = in_sizes[1] / O;       // 567
    const int maxd    = K / 9;                 // 63
    const int max_pad = 4 * maxd;              // 252
    const int BC      = in_sizes[0] / LN;      // 24
    const int T       = out_size / (BC * O);   // 450

    int2* params = (int2*)d_ws;                // O * 8 bytes = 26 KB

    parse_w_kernel<<<(O + 255) / 256, 256, 0, stream>>>(W, O, K, max_pad, params);

    const size_t smem = (size_t)(LN + 2 * max_pad + 4) * sizeof(float);
    rocket_kernel<<<BC * O, THREADS, smem, stream>>>(X, b, params, out, O, T, max_pad);
}

// Round 2
// 152.686 us; speedup vs baseline: 1.5800x; 1.5800x over previous
//
#include <hip/hip_runtime.h>

#define LN 512        // MAX_IN_LENGTH (fixed by the reference)
#define NK 84         // number of base kernels = C(9,3)
#define THREADS 256

// ---------------------------------------------------------------------------
// Parse: one 64-lane wave per channel-group g (84 channels sharing dilation
// and bias). Row o = g*84 is combo (0,1,2): first tap (value 2.0) sits at
// p0 = max_pad - 4*d, a multiple of 4. Lane j probes W[g*84][4*j]; ballot +
// ffs finds p0 in ONE parallel load instead of a serial scan.
// ---------------------------------------------------------------------------
__global__ void parse_groups(const float* __restrict__ W, int K, int maxd,
                             int n_groups, int* __restrict__ dil) {
    const int g = blockIdx.x;
    if (g >= n_groups) return;
    const int j = threadIdx.x;                 // 0..63
    const float* row = W + (size_t)g * NK * K;
    float v = (j <= maxd && 4 * j < K) ? row[4 * j] : 0.0f;
    unsigned long long m = __ballot(v != 0.0f);
    int j0 = __ffsll((unsigned long long)m) - 1;   // first nonzero probe index
    if (j == 0) dil[g] = maxd - j0;                // d = (max_pad - 4*j0) / 4
}

// ---------------------------------------------------------------------------
// Main: one block per (bc, group). out[o,t] = bias_g - S9(t) + 3*(xa+xb+xc)
// where S9 = sum of the 9 dilated taps and (a,b,c) enumerates C(9,3) in
// lexicographic order (== the construction order of the 84 base kernels).
// Each lane holds the 9 taps for two adjacent t's in REGISTERS and emits all
// 84 rows; stores are contiguous float2 per row (rows for one group are
// contiguous in memory: o = g*84+k).
// ---------------------------------------------------------------------------
__global__ __launch_bounds__(THREADS) void rocket_main(
    const float* __restrict__ X, const float* __restrict__ bias,
    const int* __restrict__ dil, float* __restrict__ out,
    int O, int T, int max_pad, int n_groups) {
    extern __shared__ float xs[];   // max_pad | LN | max_pad (zero-padded edges)

    const int g  = blockIdx.x % n_groups;
    const int bc = blockIdx.x / n_groups;

    for (int i = threadIdx.x; i < max_pad; i += THREADS) {
        xs[i] = 0.0f;
        xs[max_pad + LN + i] = 0.0f;
    }
    const float* xrow = X + (size_t)bc * LN;
    for (int i = threadIdx.x; i < LN; i += THREADS) {
        xs[max_pad + i] = xrow[i];
    }
    __syncthreads();

    const int   d  = dil[g];
    const float bv = bias[(size_t)g * NK];    // constant across the 84 channels
    float* const outg = out + ((size_t)bc * O + (size_t)g * NK) * T;

    const int pairs = T >> 1;
    for (int p = threadIdx.x; p < pairs; p += THREADS) {
        const int t0   = 2 * p;
        const int base = max_pad + t0 - 4 * d;
        float tx[9], ty[9];
        float s9x = 0.0f, s9y = 0.0f;
#pragma unroll
        for (int j = 0; j < 9; ++j) {
            tx[j] = xs[base + j * d];
            ty[j] = xs[base + j * d + 1];
            s9x += tx[j];
            s9y += ty[j];
        }
        const float bx = bv - s9x;
        const float by = bv - s9y;

        float* op = outg + t0;
#pragma unroll
        for (int a = 0; a < 7; ++a) {
#pragma unroll
            for (int b2 = a + 1; b2 < 8; ++b2) {
                const float px = tx[a] + tx[b2];
                const float py = ty[a] + ty[b2];
#pragma unroll
                for (int c = b2 + 1; c < 9; ++c) {
                    const float ox = fmaf(3.0f, px + tx[c], bx);
                    const float oy = fmaf(3.0f, py + ty[c], by);
                    *(float2*)op = make_float2(ox, oy);
                    op += T;                   // next channel row (contiguous group)
                }
            }
        }
    }

    // odd-T tail (dead for T=450, kept for shape safety)
    if ((T & 1) && threadIdx.x == 0) {
        const int t    = T - 1;
        const int base = max_pad + t - 4 * d;
        float tx[9]; float s9 = 0.0f;
#pragma unroll
        for (int j = 0; j < 9; ++j) { tx[j] = xs[base + j * d]; s9 += tx[j]; }
        const float bx = bv - s9;
        float* op = outg + t;
        for (int a = 0; a < 7; ++a)
            for (int b2 = a + 1; b2 < 8; ++b2)
                for (int c = b2 + 1; c < 9; ++c) {
                    *op = fmaf(3.0f, tx[a] + tx[b2] + tx[c], bx);
                    op += T;
                }
    }
}

extern "C" void kernel_launch(void* const* d_in, const int* in_sizes, int n_in,
                              void* d_out, int out_size, void* d_ws, size_t ws_size,
                              hipStream_t stream) {
    const float* X = (const float*)d_in[0];
    const float* W = (const float*)d_in[1];
    const float* b = (const float*)d_in[2];
    float* out = (float*)d_out;

    const int O        = in_sizes[2];           // 3276
    const int K        = in_sizes[1] / O;       // 567
    const int maxd     = K / 9;                 // 63
    const int max_pad  = 4 * maxd;              // 252
    const int BC       = in_sizes[0] / LN;      // 24
    const int T        = out_size / (BC * O);   // 450
    const int n_groups = O / NK;                // 39

    int* dil = (int*)d_ws;                      // n_groups ints

    parse_groups<<<n_groups, 64, 0, stream>>>(W, K, maxd, n_groups, dil);

    const size_t smem = (size_t)(LN + 2 * max_pad + 4) * sizeof(float);
    rocket_main<<<BC * n_groups, THREADS, smem, stream>>>(
        X, b, dil, out, O, T, max_pad, n_groups);
}